// Round 5
// baseline (538.119 us; speedup 1.0000x reference)
//
#include <hip/hip_runtime.h>

#define HIDDEN 128
#define TSTEPS 512
#define NFUT 50
#define BR 16          // batch rows per block
#define THREADS 512    // 8 waves
#define HPITCH 136     // h row pitch in bf16 (272B rows: 16B-aligned for b128)

typedef __bf16 bf16x8 __attribute__((ext_vector_type(8)));
typedef float floatx4 __attribute__((ext_vector_type(4)));

union B8 { int4 i; bf16x8 v; };

#if defined(__has_builtin)
#  if __has_builtin(__builtin_amdgcn_exp2f)
#    define EXP2F(x) __builtin_amdgcn_exp2f(x)
#  else
#    define EXP2F(x) exp2f(x)
#  endif
#  if __has_builtin(__builtin_amdgcn_rcpf)
#    define RCPF(x) __builtin_amdgcn_rcpf(x)
#  else
#    define RCPF(x) (1.0f / (x))
#  endif
#else
#  define EXP2F(x) exp2f(x)
#  define RCPF(x) (1.0f / (x))
#endif

#define L2E  1.4426950408889634f
#define L2E2 2.8853900817779268f

__global__ __launch_bounds__(THREADS, 2)
void lstm_forecast_kernel(const float* __restrict__ x,
                          const float* __restrict__ W_ih,
                          const float* __restrict__ W_hh,
                          const float* __restrict__ b_ih,
                          const float* __restrict__ b_hh,
                          const float* __restrict__ fc_w,
                          const float* __restrict__ fc_b,
                          float* __restrict__ out) {
    // LDS: xa 64.1KB + h 8.5KB + fcw 1KB ~= 74KB -> 1 block/CU
    __shared__ __align__(16) uint2  xa[(TSTEPS + 1) * BR];  // +1 zero pad row for hoisted t+1 read
    __shared__ __align__(16) __bf16 h_lds[2][BR * HPITCH];  // double-buffered h
    __shared__ __align__(16) float  fcw_lds[2][HIDDEN];

    const int tid  = threadIdx.x;
    const int wave = tid >> 6;
    const int lane = tid & 63;
    const int quad = lane >> 4;
    const int l15  = lane & 15;
    const int rb   = blockIdx.x * BR;

    if (tid < 256) fcw_lds[tid >> 7][tid & 127] = fc_w[tid];

    // ---- stage x as bf16 hi/lo splits: xa[t][row]; row TSTEPS zeroed ----
    {
        const int row = tid & 15;
        for (int tb = tid >> 4; tb < TSTEPS + 1; tb += THREADS >> 4) {
            float2 xv = make_float2(0.f, 0.f);
            if (tb < TSTEPS)
                xv = *(const float2*)&x[(size_t)(rb + row) * (2 * TSTEPS) + tb * 2];
            __bf16 x0h = (__bf16)xv.x, x1h = (__bf16)xv.y;
            __bf16 x0r = (__bf16)(xv.x - (float)x0h);
            __bf16 x1r = (__bf16)(xv.y - (float)x1h);
            uint2 d;
            d.x = (unsigned)__builtin_bit_cast(unsigned short, x0h) |
                  ((unsigned)__builtin_bit_cast(unsigned short, x1h) << 16);
            d.y = (unsigned)__builtin_bit_cast(unsigned short, x0r) |
                  ((unsigned)__builtin_bit_cast(unsigned short, x1r) << 16);
            xa[tb * BR + row] = d;
        }
    }
    for (int i = tid; i < BR * HPITCH; i += THREADS) h_lds[0][i] = (__bf16)0.0f;

    // ---- weights -> registers, pre-scaled so MFMA outputs are exp2-ready ----
    bf16x8 bfrag[4][4];
    B8 bfx[4];
    float wih0[4], wih1[4], bsum[4], gs[4];
    const int u = wave * 16 + l15;
    const float fcb0 = fc_b[0], fcb1 = fc_b[1];
#pragma unroll
    for (int g = 0; g < 4; ++g) {
        gs[g] = (g == 2) ? -L2E2 : -L2E;
        const int cg = g * HIDDEN + u;
        wih0[g] = W_ih[cg * 2 + 0];
        wih1[g] = W_ih[cg * 2 + 1];
        bsum[g] = b_ih[cg] + b_hh[cg];
#pragma unroll
        for (int ks = 0; ks < 4; ++ks) {
            const float* wp = W_hh + (size_t)cg * HIDDEN + ks * 32 + quad * 8;
            bf16x8 bb;
#pragma unroll
            for (int j = 0; j < 8; ++j) bb[j] = (__bf16)(gs[g] * wp[j]);
            bfrag[g][ks] = bb;
        }
        B8 t; t.i = make_int4(0, 0, 0, 0);
        if (quad == 0) {
            const float w0s = gs[g] * wih0[g], w1s = gs[g] * wih1[g], bss = gs[g] * bsum[g];
            __bf16 w0h = (__bf16)w0s, w1h = (__bf16)w1s;
            __bf16 w0l = (__bf16)(w0s - (float)w0h);
            __bf16 w1l = (__bf16)(w1s - (float)w1h);
            __bf16 bh  = (__bf16)bss;
            __bf16 bl  = (__bf16)(bss - (float)bh);
            bf16x8 bv = {w0h, w1h, bh, bl, w0h, w1h, w0l, w1l};
            t.v = bv;
        }
        bfx[g] = t;
    }

    const unsigned ones2 = 0x3F803F80u;  // bf16(1.0) x2

    float cst[4] = {0.f, 0.f, 0.f, 0.f};

    // elementwise with Montgomery-batched reciprocals (2 rcp per 4 states)
    auto ew = [&](floatx4 a0, floatx4 a1, floatx4 a2, floatx4 a3, __bf16* hd) {
        float ea[4], eb[4], ec[4], A1[4], B1[4], C1[4], D[4];
#pragma unroll
        for (int r = 0; r < 4; ++r) {
            ea[r] = EXP2F(a0[r]);           // e^-i (scaled)
            eb[r] = EXP2F(a2[r]);           // e^-2g
            ec[r] = EXP2F(a1[r]);           // e^-f
            A1[r] = 1.f + ea[r];
            B1[r] = 1.f + eb[r];
            C1[r] = 1.f + ec[r];
            D[r]  = A1[r] * B1[r] * C1[r];
        }
        // batch-invert D[0..3]: 1 rcp + 9 muls
        const float p2 = D[0] * D[1], p3 = p2 * D[2], p4 = p3 * D[3];
        const float I  = RCPF(p4);
        const float R3 = I * p3;
        const float I3 = I * D[3];
        const float Rr2 = I3 * p2;
        const float I2 = I3 * D[2];
        const float R1 = I2 * D[0];
        const float R0 = I2 * D[1];
        const float Rr[4] = {R0, R1, Rr2, R3};
        float cnv[4];
#pragma unroll
        for (int r = 0; r < 4; ++r) {
            const float sfv = (A1[r] * B1[r]) * Rr[r];          // sigmoid(f)
            const float igv = (1.f - eb[r]) * (C1[r] * Rr[r]);  // sigmoid(i)*tanh(g)
            cnv[r] = fmaf(sfv, cst[r], igv);
            cst[r] = cnv[r];
        }
        float ed[4], eo[4], E[4];
#pragma unroll
        for (int r = 0; r < 4; ++r) {
            const float arg = fminf(-L2E2 * cnv[r], 29.f);  // c clamped at -10 (tanh err < 4e-9)
            ed[r] = EXP2F(arg);
            eo[r] = EXP2F(a3[r]);                           // e^-o
            E[r]  = (1.f + ed[r]) * (1.f + eo[r]);
        }
        const float q2 = E[0] * E[1], q3 = q2 * E[2], q4 = q3 * E[3];
        const float J  = RCPF(q4);
        const float S3 = J * q3;
        const float J3 = J * E[3];
        const float S2 = J3 * q2;
        const float J2 = J3 * E[2];
        const float S1 = J2 * E[0];
        const float S0 = J2 * E[1];
        const float S[4] = {S0, S1, S2, S3};
#pragma unroll
        for (int r = 0; r < 4; ++r) {
            const float hn = (1.f - ed[r]) * S[r];  // sigmoid(o)*tanh(c)
            hd[(quad * 4 + r) * HPITCH + u] = (__bf16)hn;
        }
    };

    __syncthreads();

    // ---- prologue: acc-init(0) = x(0) + bias via hoisted x-MFMA ----
    floatx4 acc[4];
    const floatx4 z = {0.f, 0.f, 0.f, 0.f};
    {
        const uint2 xd = xa[0 * BR + l15];
        B8 xf; xf.i = make_int4((int)xd.x, (int)ones2, (int)xd.y, (int)xd.x);
#pragma unroll
        for (int g = 0; g < 4; ++g)
            acc[g] = __builtin_amdgcn_mfma_f32_16x16x32_bf16(xf.v, bfx[g].v, z, 0, 0, 0);
    }

    // encode step: consume acc-init, produce next acc-init BEFORE the barrier
    auto cellE = [&](const __bf16* hs, __bf16* hd, int tn) {
        bf16x8 af[4];
#pragma unroll
        for (int ks = 0; ks < 4; ++ks)
            af[ks] = *(const bf16x8*)&hs[l15 * HPITCH + ks * 32 + quad * 8];
#pragma unroll
        for (int ks = 0; ks < 4; ++ks)
#pragma unroll
            for (int g = 0; g < 4; ++g)
                acc[g] = __builtin_amdgcn_mfma_f32_16x16x32_bf16(af[ks], bfrag[g][ks], acc[g], 0, 0, 0);
        ew(acc[0], acc[1], acc[2], acc[3], hd);
        // hoisted x+bias MFMA for step tn (MFMA pipe idle during ew/barrier window)
        {
            const uint2 xd = xa[tn * BR + l15];   // tn==TSTEPS reads zero pad (result discarded)
            B8 xf; xf.i = make_int4((int)xd.x, (int)ones2, (int)xd.y, (int)xd.x);
#pragma unroll
            for (int g = 0; g < 4; ++g)
                acc[g] = __builtin_amdgcn_mfma_f32_16x16x32_bf16(xf.v, bfx[g].v, z, 0, 0, 0);
        }
        __syncthreads();
    };

    // ================= encode: 512 steps =================
    for (int t = 0; t < TSTEPS; t += 2) {
        cellE(h_lds[0], h_lds[1], t + 1);
        cellE(h_lds[1], h_lds[0], t + 2);
    }

    // ========== transition: fold fc into weights =========
    // W_eff = gs*(W_hh + W_ih*fc_w) ; b_eff = gs*(b + W_ih*fc_b)
#pragma unroll
    for (int g = 0; g < 4; ++g) {
        const float bs2 = gs[g] * (bsum[g] + wih0[g] * fcb0 + wih1[g] * fcb1);
#pragma unroll
        for (int ks = 0; ks < 4; ++ks) {
            const int k0 = ks * 32 + quad * 8;
            bf16x8 bb = bfrag[g][ks];
#pragma unroll
            for (int j = 0; j < 8; ++j) {
                const float wv = (float)bb[j] + gs[g] * (wih0[g] * fcw_lds[0][k0 + j]
                                                      + wih1[g] * fcw_lds[1][k0 + j]);
                bb[j] = (__bf16)wv;
            }
            bfrag[g][ks] = bb;
        }
        // bias-only MFMA fragment for forecast init
        B8 t; t.i = make_int4(0, 0, 0, 0);
        if (quad == 0) {
            __bf16 bh = (__bf16)bs2;
            __bf16 bl = (__bf16)(bs2 - (float)bh);
            bf16x8 bv = {(__bf16)0.f, (__bf16)0.f, bh, bl,
                         (__bf16)0.f, (__bf16)0.f, (__bf16)0.f, (__bf16)0.f};
            t.v = bv;
        }
        bfx[g] = t;
    }
    // forecast A-frag for bias init: 1.0 at k=2,3 (all quads; off-quad0 B rows are zero)
    B8 xfF; xfF.i = make_int4(0, (int)ones2, 0, 0);

    // init acc for first forecast step (bias via MFMA, replaces the discarded pad init)
#pragma unroll
    for (int g = 0; g < 4; ++g)
        acc[g] = __builtin_amdgcn_mfma_f32_16x16x32_bf16(xfF.v, bfx[g].v, z, 0, 0, 0);

    auto cellF = [&](const __bf16* hs, __bf16* hd) {
        bf16x8 af[4];
#pragma unroll
        for (int ks = 0; ks < 4; ++ks)
            af[ks] = *(const bf16x8*)&hs[l15 * HPITCH + ks * 32 + quad * 8];
#pragma unroll
        for (int ks = 0; ks < 4; ++ks)
#pragma unroll
            for (int g = 0; g < 4; ++g)
                acc[g] = __builtin_amdgcn_mfma_f32_16x16x32_bf16(af[ks], bfrag[g][ks], acc[g], 0, 0, 0);
        ew(acc[0], acc[1], acc[2], acc[3], hd);
#pragma unroll
        for (int g = 0; g < 4; ++g)   // hoisted bias init for next step
            acc[g] = __builtin_amdgcn_mfma_f32_16x16x32_bf16(xfF.v, bfx[g].v, z, 0, 0, 0);
        __syncthreads();
    };

    // y output only (no feedback): wave0 computes while others run MFMA
    auto emitY = [&](const __bf16* hs, int f) {
        if (wave == 0) {
            const int r = lane & 15, seg = lane >> 4;
            const __bf16* hp = &hs[r * HPITCH + seg * 32];
            float p0 = 0.f, p1 = 0.f;
#pragma unroll
            for (int js = 0; js < 4; ++js) {
                bf16x8 hv = *(const bf16x8*)&hp[js * 8];
                const float4* f0 = (const float4*)&fcw_lds[0][seg * 32 + js * 8];
                const float4* f1 = (const float4*)&fcw_lds[1][seg * 32 + js * 8];
                float4 a0 = f0[0], b0 = f0[1], a1 = f1[0], b1 = f1[1];
                p0 += (float)hv[0]*a0.x + (float)hv[1]*a0.y + (float)hv[2]*a0.z + (float)hv[3]*a0.w
                    + (float)hv[4]*b0.x + (float)hv[5]*b0.y + (float)hv[6]*b0.z + (float)hv[7]*b0.w;
                p1 += (float)hv[0]*a1.x + (float)hv[1]*a1.y + (float)hv[2]*a1.z + (float)hv[3]*a1.w
                    + (float)hv[4]*b1.x + (float)hv[5]*b1.y + (float)hv[6]*b1.z + (float)hv[7]*b1.w;
            }
            p0 += __shfl_xor(p0, 16); p0 += __shfl_xor(p0, 32);
            p1 += __shfl_xor(p1, 16); p1 += __shfl_xor(p1, 32);
            if (seg == 0) {
                float* op = &out[(size_t)(rb + r) * (2 * NFUT) + f * 2];
                op[0] = p0 + fcb0;
                op[1] = p1 + fcb1;
            }
        }
    };

    // ================= forecast: 50 steps ================
    for (int f = 0; f < NFUT; f += 2) {
        emitY(h_lds[0], f);
        cellF(h_lds[0], h_lds[1]);
        emitY(h_lds[1], f + 1);
        cellF(h_lds[1], h_lds[0]);
    }
}

extern "C" void kernel_launch(void* const* d_in, const int* in_sizes, int n_in,
                              void* d_out, int out_size, void* d_ws, size_t ws_size,
                              hipStream_t stream) {
    const float* x    = (const float*)d_in[0];
    const float* W_ih = (const float*)d_in[1];
    const float* W_hh = (const float*)d_in[2];
    const float* b_ih = (const float*)d_in[3];
    const float* b_hh = (const float*)d_in[4];
    const float* fc_w = (const float*)d_in[5];
    const float* fc_b = (const float*)d_in[6];
    float* out = (float*)d_out;

    const int B = in_sizes[0] / (TSTEPS * 2);   // 4096
    const int grid = B / BR;                    // 256 blocks, 1 per CU
    lstm_forecast_kernel<<<grid, THREADS, 0, stream>>>(x, W_ih, W_hh, b_ih, b_hh, fc_w, fc_b, out);
}